// Round 34
// baseline (159.213 us; speedup 1.0000x reference)
//
#include <hip/hip_runtime.h>
#include <hip/hip_bf16.h>
#include <math.h>

// Problem constants
#define NN   2048
#define FB   4
#define DD   256
#define EE   65536
#define NT   (NN*FB)
#define FFD  2048

typedef unsigned int u32;
typedef unsigned short u16;
typedef __attribute__((ext_vector_type(4))) float f32x4;
typedef __attribute__((ext_vector_type(8))) short bf16x8;

// weight buffer offsets (bf16 elements)
#define OFF_W2   0
#define OFF_G1   524288
#define OFF_G2   655360
#define OFF_G3   917504
#define OFF_G4   1179648
#define WBF_TOT  1441792

// ---------------- static device scratch ----------------
__device__ float g_A[768], g_B[768];
__device__ float g_coefA[4], g_coefC[4];
__device__ float g_meanv[6], g_G[36];
__device__ float g_Vx[8*DD];
__device__ u16   g_w1vh[FFD*8];             // W1V' bf16 (b1 folded into col 7)
__device__ float g_cc[NT*8];                // per-token LN1 coefficients
__device__ u16   g_xmh[NN*DD];
__device__ u16   g_hsh[NN*512];
__device__ u16   g_xgh[NN*512];
__device__ u16   g_wbf[WBF_TOT];
__device__ __align__(64) int g_degp[NN*16]; // line-padded atomic counters
__device__ __align__(64) int g_curp[NN*16];
__device__ int   g_off[NN+1], g_adj[EE];
__device__ float g_dinv[NN];

// ---------------- helpers ----------------
__device__ __forceinline__ u16 f2bf(float x) {
  u32 u = __float_as_uint(x);
  return (u16)((u + 0x7FFFu + ((u >> 16) & 1u)) >> 16);
}
__device__ __forceinline__ float bfl(u32 v) { return __uint_as_float(v << 16); }
__device__ __forceinline__ float bfh(u32 v) { return __uint_as_float(v & 0xffff0000u); }
__device__ __forceinline__ void gl_lds16(const void* g, void* l) {
  __builtin_amdgcn_global_load_lds(
      (const __attribute__((address_space(1))) u32*)g,
      (__attribute__((address_space(3))) u32*)l, 16, 0, 0);
}
__device__ __forceinline__ float qred(float v) {
  v += __shfl_xor(v, 1, 64);
  v += __shfl_xor(v, 2, 64);
  return v;
}
__device__ __forceinline__ void acc8(const uint4 v, float* a) {
  a[0]+=bfl(v.x); a[1]+=bfh(v.x);
  a[2]+=bfl(v.y); a[3]+=bfh(v.y);
  a[4]+=bfl(v.z); a[5]+=bfh(v.z);
  a[6]+=bfl(v.w); a[7]+=bfh(v.w);
}

// ========= FUSE-1: prep_ab (blk 0..11) || zero counters (blk 12..139) =========
__global__ __launch_bounds__(256) void k_fuse1(const float* __restrict__ ipw,
    const float* __restrict__ ipb, const float* __restrict__ linw,
    const float* __restrict__ linb) {
  __shared__ __align__(16) float sm[512];
  const int b = blockIdx.x, t = threadIdx.x;
  if (b < 12) {
    float* lw = sm; float* lb = sm + 256;
    lw[t] = linw[t]; lb[t] = linb[t];
    __syncthreads();
    int j = b*64 + (t>>2), c = t&3;
    const float4* row = (const float4*)&ipw[j*256 + c*64];
    float a = 0.f, bb = 0.f;
    #pragma unroll
    for (int q = 0; q < 16; q++) {
      float4 v = row[q]; int d0 = c*64 + q*4;
      a  += v.x*lw[d0] + v.y*lw[d0+1] + v.z*lw[d0+2] + v.w*lw[d0+3];
      bb += v.x*lb[d0] + v.y*lb[d0+1] + v.z*lb[d0+2] + v.w*lb[d0+3];
    }
    a = qred(a); bb = qred(bb);
    if (c == 0) { g_A[j] = a; g_B[j] = bb + ipb[j]; }
  } else {
    int i = (b - 12)*256 + t;
    if (i < NN*16) { g_degp[i] = 0; g_curp[i] = 0; }
  }
}

// ================= FUSE-2: prep_head (blk 0)  ||  deg (blk 1..256) =================
__global__ __launch_bounds__(256) void k_fuse2(const float* __restrict__ outw,
    const float* __restrict__ outb, const float* __restrict__ linw,
    const float* __restrict__ linb, const float* __restrict__ g1,
    const float* __restrict__ b1ln, const int* __restrict__ edges) {
  __shared__ __align__(16) float sm[512 + 4*27];
  const int b = blockIdx.x, t = threadIdx.x;
  if (b == 0) {
    int lane = t & 63, w = t >> 6;
    {
      float aq = g_A[w*64 + lane], ak = g_A[256 + w*64 + lane], bq = g_B[w*64 + lane];
      float pa = aq * ak, pc = bq * ak;
      #pragma unroll
      for (int o = 32; o > 0; o >>= 1) { pa += __shfl_down(pa, o, 64); pc += __shfl_down(pc, o, 64); }
      if (lane == 0) { g_coefA[w] = pa * 0.125f; g_coefC[w] = pc * 0.125f; }
    }
    float* A2 = sm; float* B2 = sm + 256; float* wred = sm + 512;
    A2[t] = g_A[512 + t]; B2[t] = g_B[512 + t];
    __syncthreads();
    const int d = t;
    const float4* row = (const float4*)&outw[d*256];
    float pv[4] = {0,0,0,0}, q0 = 0.f;
    #pragma unroll 8
    for (int q = 0; q < 64; q++) {
      float4 v = row[q]; int e0 = q*4; int h = q >> 4;
      pv[h] += v.x*A2[e0] + v.y*A2[e0+1] + v.z*A2[e0+2] + v.w*A2[e0+3];
      q0    += v.x*B2[e0] + v.y*B2[e0+1] + v.z*B2[e0+2] + v.w*B2[e0+3];
    }
    q0 += outb[d];
    float c0 = linb[d] + q0;
    float Mv[6] = { linw[d], pv[0], pv[1], pv[2], pv[3], c0 };
    float vals[27];
    { int idx = 0;
      #pragma unroll
      for (int k = 0; k < 6; k++) vals[idx++] = Mv[k];
      #pragma unroll
      for (int k = 0; k < 6; k++)
        #pragma unroll
        for (int l = 0; l < 6; l++) if (l >= k) vals[idx++] = Mv[k]*Mv[l];
    }
    #pragma unroll
    for (int k2 = 0; k2 < 27; k2++) {
      float v = vals[k2];
      #pragma unroll
      for (int o = 32; o > 0; o >>= 1) v += __shfl_down(v, o, 64);
      if (lane == 0) wred[w*27 + k2] = v;
    }
    __syncthreads();
    if (t < 27) {
      float s = wred[t] + wred[27 + t] + wred[54 + t] + wred[81 + t];
      if (t < 6) g_meanv[t] = s * (1.f/256.f);
      else {
        int p = t - 6, k = 0;
        while (p >= 6 - k) { p -= 6 - k; k++; }
        int l = k + p;
        g_G[k*6+l] = s; g_G[l*6+k] = s;
      }
    }
    #pragma unroll
    for (int k = 0; k < 6; k++) g_Vx[k*256 + d] = Mv[k] * g1[d];
    g_Vx[6*256 + d] = g1[d];
    g_Vx[7*256 + d] = b1ln[d];
  } else {
    int e = (b - 1)*256 + t;
    atomicAdd(&g_degp[edges[EE + e] * 16], 1);
  }
}

// ===== FUSE-3: attn_m + cc (0..511) || w1v->bf16+b1fold (512..543) || scan (544) || cvt (545..1952) =====
// cc computation folded from old k_fuse4: each attn block owns exactly tokens b*16..b*16+15
// (tok = tuple>>2), holds feat in LDS, and computes all 4 heads' m -> compute cc in-block.
__global__ __launch_bounds__(256) void k_fuse3(const float* __restrict__ feat,
    const float* __restrict__ w1, const float* __restrict__ fb1,
    const float* __restrict__ w2c, const float* __restrict__ W1c,
    const float* __restrict__ W2c, const float* __restrict__ W3c,
    const float* __restrict__ W4c) {
  __shared__ __align__(16) char smraw[35072];
  const int b = blockIdx.x, t = threadIdx.x;
  if (b < 512) {
    float* fs   = (float*)smraw;      // 8192 floats
    float* ss   = fs + 8192;          // 256
    float* ww   = ss + 256;           // 256
    float* marr = ww + 256;           // 64: m for this block's 64 tuples
    for (int i = t; i < 2048; i += 256) {
      const float4 v = *(const float4*)&feat[i*4];
      fs[0*2048+i] = v.x; fs[1*2048+i] = v.y; fs[2*2048+i] = v.z; fs[3*2048+i] = v.w;
    }
    __syncthreads();
    int tuple = b * 64 + (t >> 2);
    int c = t & 3;
    int h = tuple & 3, f = (tuple >> 2) & 3, n = tuple >> 4;
    float fi = fs[f*2048 + n];
    float tt = g_coefA[h] * fi + g_coefC[h];
    float s = 0.f, wsum = 0.f;
    int j0 = c * 512;
    for (int j = j0; j < j0 + 512; j++) {
      float fj = fs[f*2048 + j];
      float e = __expf(tt * fj);
      s += e; wsum += e * fj;
    }
    ss[(t>>2)*4 + c] = s; ww[(t>>2)*4 + c] = wsum;
    __syncthreads();
    if (c == 0) {
      float S = ss[(t>>2)*4] + ss[(t>>2)*4+1] + ss[(t>>2)*4+2] + ss[(t>>2)*4+3];
      float W = ww[(t>>2)*4] + ww[(t>>2)*4+1] + ww[(t>>2)*4+2] + ww[(t>>2)*4+3];
      marr[t>>2] = W / S;
    }
    __syncthreads();
    if (t < 16) {
      int tok = b*16 + t;
      int n2 = tok >> 2, f2 = tok & 3;
      float fi2 = fs[f2*2048 + n2];
      float u[6] = { fi2, marr[t*4+0], marr[t*4+1], marr[t*4+2], marr[t*4+3], 1.f };
      float mu = 0.f;
      #pragma unroll
      for (int k = 0; k < 6; k++) mu += g_meanv[k] * u[k];
      float q = 0.f;
      for (int k = 0; k < 6; k++)
        for (int l = 0; l < 6; l++) q += u[k] * g_G[k*6+l] * u[l];
      q *= (1.f/256.f);
      float var = q - mu * mu;
      float sc = rsqrtf(var + 1e-5f);
      float4 w0; w0.x = fi2*sc; w0.y = u[1]*sc; w0.z = u[2]*sc; w0.w = u[3]*sc;
      float4 w1v; w1v.x = u[4]*sc; w1v.y = sc; w1v.z = -mu*sc; w1v.w = 1.f;
      *(float4*)&g_cc[tok*8]     = w0;
      *(float4*)&g_cc[tok*8 + 4] = w1v;
    }
  } else if (b < 544) {
    // W1V'[j][k] = W1[j,:]·Vx_k  (+ b1[j] folded into k=7); bf16 out
    float* vx = (float*)smraw;
    #pragma unroll
    for (int k = 0; k < 8; k++) vx[k*256 + t] = g_Vx[k*256 + t];
    __syncthreads();
    int j = (b - 512)*64 + (t>>2), c = t&3;
    const float4* row = (const float4*)&w1[j*256 + c*64];
    float acc[8] = {0,0,0,0,0,0,0,0};
    #pragma unroll
    for (int q = 0; q < 16; q++) {
      float4 v = row[q]; int d0 = c*64 + q*4;
      #pragma unroll
      for (int k = 0; k < 8; k++)
        acc[k] += v.x*vx[k*256+d0] + v.y*vx[k*256+d0+1]
                + v.z*vx[k*256+d0+2] + v.w*vx[k*256+d0+3];
    }
    #pragma unroll
    for (int k = 0; k < 8; k++) acc[k] = qred(acc[k]);
    if (c == 0) {
      acc[7] += fb1[j];
      uint4 r;
      r.x = ((u32)f2bf(acc[1])<<16) | f2bf(acc[0]);
      r.y = ((u32)f2bf(acc[3])<<16) | f2bf(acc[2]);
      r.z = ((u32)f2bf(acc[5])<<16) | f2bf(acc[4]);
      r.w = ((u32)f2bf(acc[7])<<16) | f2bf(acc[6]);
      *(uint4*)&g_w1vh[j*8] = r;
    }
  } else if (b == 544) {
    int* wt = (int*)smraw;
    int base = t * 8;
    int v[8], ex[8], sum = 0;
    #pragma unroll
    for (int i = 0; i < 8; i++) { ex[i] = sum; v[i] = g_degp[(base+i)*16]; sum += v[i]; }
    int lane = t & 63, w = t >> 6;
    int inc = sum;
    #pragma unroll
    for (int o = 1; o < 64; o <<= 1) { int x = __shfl_up(inc, o, 64); if (lane >= o) inc += x; }
    if (lane == 63) wt[w] = inc;
    __syncthreads();
    int wb = 0;
    for (int j = 0; j < w; j++) wb += wt[j];
    int excl = wb + inc - sum;
    #pragma unroll
    for (int i = 0; i < 8; i++) {
      g_off[base+i] = excl + ex[i];
      g_dinv[base+i] = rsqrtf((float)(v[i] + 1));
    }
    if (t == 255) g_off[NN] = wb + inc;
  } else {
    int i = ((b - 545)*256 + t) * 4;
    const float* src; int off;
    if (i < OFF_G1)      { src = w2c; off = OFF_W2; }
    else if (i < OFF_G2) { src = W1c; off = OFF_G1; }
    else if (i < OFF_G3) { src = W2c; off = OFF_G2; }
    else if (i < OFF_G4) { src = W3c; off = OFF_G3; }
    else                 { src = W4c; off = OFF_G4; }
    float4 v = *(const float4*)&src[i - off];
    ushort4 r;
    r.x = f2bf(v.x); r.y = f2bf(v.y); r.z = f2bf(v.z); r.w = f2bf(v.w);
    *(ushort4*)&g_wbf[i] = r;
  }
}

// ====== FFN2 (on-the-fly h1) + LN2 + mean + relu -> g_xmh  ||  CSR fill (blk 512..767) ======
__global__ __launch_bounds__(256) void k_ffnln(const float* __restrict__ fb2,
    const float* __restrict__ ln2g, const float* __restrict__ ln2b,
    const int* __restrict__ edges) {
  __shared__ __align__(16) char smp[74752];
  u16*   Bsl  = (u16*)smp;                 // 64 KB: W2 tile [256 cols][128 k], swizzled 16B slots
  u16*   Asl  = (u16*)(smp + 65536);       // 4 KB:  h1 tile [16 rows][128 k]
  u16*   w1sl = (u16*)(smp + 69632);       // 4 KB:  2 x [128 rows][8] W1V' slices
  float* ccs  = (float*)(smp + 73728);     // 512 B: cc [16][8]
  float* part = (float*)(smp + 74240);     // 512 B: [4 waves][16 rows][2]

  const int b = blockIdx.x, t = threadIdx.x;
  if (b >= 512) {
    int e = (b - 512)*256 + t;
    int s = edges[e], d = edges[EE + e];
    int pos = atomicAdd(&g_curp[d*16], 1);
    g_adj[g_off[d] + pos] = s;
    return;
  }
  const int w = t >> 6, lane = t & 63, fr = lane & 15, gk = lane >> 4;
  const int tok0 = b * 16;
  const u16* W2p = g_wbf + OFF_W2;

  if (t < 32) ((float4*)ccs)[t] = ((const float4*)&g_cc[tok0*8])[t];
  if (w == 1) {
    #pragma unroll
    for (int hh = 0; hh < 2; hh++) {
      int p = hh*64 + lane;
      int q = (p & ~7) | ((p ^ (p >> 3)) & 7);   // involution
      gl_lds16(g_w1vh + (size_t)q*8, w1sl + (hh << 9));
    }
  }
  __syncthreads();

  const int arow = t >> 4, aslot = t & 15;
  float ac[8];
  #pragma unroll
  for (int k = 0; k < 8; k++) ac[k] = ccs[arow*8 + k];

  f32x4 acc[4] = {};
  for (int it = 0; it < 16; it++) {
    const int k0 = it << 7;
    const int cur = it & 1;
    #pragma unroll
    for (int c = 0; c < 16; c++) {
      int col0 = (w << 6) + (c << 2);
      int colL = col0 + (lane >> 4);
      int p = lane & 15;
      int q = (p & 8) | ((p ^ (colL & 7)) & 7);
      gl_lds16(W2p + (size_t)colL*FFD + k0 + q*8, Bsl + (col0 << 7));
    }
    if (w == 1 && it < 15) {
      #pragma unroll
      for (int hh = 0; hh < 2; hh++) {
        int p = hh*64 + lane;
        int q = (p & ~7) | ((p ^ (p >> 3)) & 7);
        gl_lds16(g_w1vh + (size_t)(k0 + 128 + q)*8, w1sl + ((cur ^ 1) << 10) + (hh << 9));
      }
    }
    {
      float h[8];
      #pragma unroll
      for (int e2 = 0; e2 < 8; e2++) {
        int ph = aslot*8 + (e2 ^ (aslot & 7));
        uint4 wv = *(const uint4*)&w1sl[(cur << 10) + ph*8];
        float s = ac[0]*bfl(wv.x) + ac[1]*bfh(wv.x)
                + ac[2]*bfl(wv.y) + ac[3]*bfh(wv.y)
                + ac[4]*bfl(wv.z) + ac[5]*bfh(wv.z)
                + ac[6]*bfl(wv.w) + ac[7]*bfh(wv.w);
        h[e2] = fmaxf(s, 0.f);
      }
      uint4 r;
      r.x = ((u32)f2bf(h[1])<<16) | f2bf(h[0]);
      r.y = ((u32)f2bf(h[3])<<16) | f2bf(h[2]);
      r.z = ((u32)f2bf(h[5])<<16) | f2bf(h[4]);
      r.w = ((u32)f2bf(h[7])<<16) | f2bf(h[6]);
      int ph = (aslot & 8) | ((aslot ^ (arow & 7)) & 7);
      *(uint4*)&Asl[(arow << 7) + (ph << 3)] = r;
    }
    __syncthreads();
    #pragma unroll
    for (int kk = 0; kk < 4; kk++) {
      int qa = (kk << 2) + gk;
      int pa = (qa & 8) | ((qa ^ (fr & 7)) & 7);
      bf16x8 af = *(const bf16x8*)&Asl[(fr << 7) + (pa << 3)];
      #pragma unroll
      for (int nb = 0; nb < 4; nb++) {
        int col = (w << 6) + (nb << 4) + fr;
        int pb = (qa & 8) | ((qa ^ (col & 7)) & 7);
        bf16x8 bv = *(const bf16x8*)&Bsl[(col << 7) + (pb << 3)];
        acc[nb] = __builtin_amdgcn_mfma_f32_16x16x32_bf16(af, bv, acc[nb], 0, 0, 0);
      }
    }
    __syncthreads();
  }

  #pragma unroll
  for (int nb = 0; nb < 4; nb++) {
    int col = (w << 6) + (nb << 4) + fr;
    float fb = fb2[col];
    #pragma unroll
    for (int r = 0; r < 4; r++) {
      int row = gk*4 + r;
      float x1 = 0.f;
      #pragma unroll
      for (int k = 0; k < 8; k++) x1 += ccs[row*8 + k] * g_Vx[k*256 + col];
      acc[nb][r] += fb + x1;
    }
  }
  float s1[4] = {0,0,0,0}, s2v[4] = {0,0,0,0};
  #pragma unroll
  for (int r = 0; r < 4; r++)
    #pragma unroll
    for (int nb = 0; nb < 4; nb++) {
      float v = acc[nb][r];
      s1[r] += v; s2v[r] += v*v;
    }
  #pragma unroll
  for (int o = 1; o < 16; o <<= 1) {
    #pragma unroll
    for (int r = 0; r < 4; r++) {
      s1[r]  += __shfl_xor(s1[r],  o, 64);
      s2v[r] += __shfl_xor(s2v[r], o, 64);
    }
  }
  if (fr == 0) {
    #pragma unroll
    for (int r = 0; r < 4; r++) {
      int row = gk*4 + r;
      part[(w*16 + row)*2 + 0] = s1[r];
      part[(w*16 + row)*2 + 1] = s2v[r];
    }
  }
  __syncthreads();
  float mu[4], inv[4];
  #pragma unroll
  for (int r = 0; r < 4; r++) {
    int row = gk*4 + r;
    float S1 = 0.f, S2 = 0.f;
    #pragma unroll
    for (int wv = 0; wv < 4; wv++) {
      S1 += part[(wv*16 + row)*2 + 0];
      S2 += part[(wv*16 + row)*2 + 1];
    }
    float m = S1 * (1.f/256.f);
    mu[r] = m;
    inv[r] = rsqrtf(S2 * (1.f/256.f) - m*m + 1e-5f);
  }
  const int node = b*4 + gk;
  #pragma unroll
  for (int nb = 0; nb < 4; nb++) {
    int col = (w << 6) + (nb << 4) + fr;
    float g = ln2g[col], bb = ln2b[col];
    float m = 0.f;
    #pragma unroll
    for (int r = 0; r < 4; r++)
      m += (acc[nb][r] - mu[r]) * inv[r] * g + bb;
    g_xmh[node*256 + col] = f2bf(fmaxf(m * 0.25f, 0.f));
  }
}

// ---------------- bf16 MFMA GEMM: C[M,N] = A[M,K] @ B[N,K]^T ----------------
// 32x64 tile, BK=128, 4 waves (2x2): wave = 16 rows x 32 cols. Grid (N/64, M/32).
template<int DO_ROWSCALE, int OUT_BF16, int HAS_BIAS>
__global__ __launch_bounds__(256) void k_mm64(
    const u16* __restrict__ A, const u16* __restrict__ Bm, void* __restrict__ Cv,
    int M, int N, int K,
    const float* __restrict__ rowscale, const float* __restrict__ bias)
{
  __shared__ u16 Asl[32*128];   // 8 KB
  __shared__ u16 Bsl[64*128];   // 16 KB
  const int t = threadIdx.x;
  const int w = t >> 6, lane = t & 63;
  const int bm = blockIdx.y * 32, bn = blockIdx.x * 64;
  const int wr = w >> 1, wc = w & 1;
  const int fr = lane & 15;
  const int gk = lane >> 4;
  f32x4 acc[2] = {};
  for (int k0 = 0; k0 < K; k0 += 128) {
    #pragma unroll
    for (int c = 0; c < 2; c++) {
      int row0 = (w << 3) + (c << 2);
      int rowL = row0 + (lane >> 4);
      int p = lane & 15;
      int q = (p & 8) | ((p ^ (rowL & 7)) & 7);
      gl_lds16(A + (size_t)(bm + rowL)*K + k0 + q*8, Asl + (row0 << 7));
    }
    #pragma unroll
    for (int c = 0; c < 4; c++) {
      int row0 = (w << 4) + (c << 2);
      int rowL = row0 + (lane >> 4);
      int p = lane & 15;
      int q = (p & 8) | ((p ^ (rowL & 7)) & 7);
      gl_lds16(Bm + (size_t)(bn + rowL)*K + k0 + q*8, Bsl + (row0 << 7));
    }
    __syncthreads();
    #pragma unroll
    for (int kk = 0; kk < 4; kk++) {
      int qa = (kk << 2) + gk;
      int row = wr*16 + fr;
      int pa = (qa & 8) | ((qa ^ (row & 7)) & 7);
      bf16x8 af = *(const bf16x8*)&Asl[(row << 7) + (pa << 3)];
      #pragma unroll
      for (int nb = 0; nb < 2; nb++) {
        int col = wc*32 + nb*16 + fr;
        int pb = (qa & 8) | ((qa ^ (col & 7)) & 7);
        bf16x8 bv = *(const bf16x8*)&Bsl[(col << 7) + (pb << 3)];
        acc[nb] = __builtin_amdgcn_mfma_f32_16x16x32_bf16(af, bv, acc[nb], 0, 0, 0);
      }
    }
    __syncthreads();
  }
  #pragma unroll
  for (int r = 0; r < 4; r++) {
    int row = bm + wr*16 + gk*4 + r;
    float rs = DO_ROWSCALE ? rowscale[row] : 1.f;
    #pragma unroll
    for (int nb = 0; nb < 2; nb++) {
      int col = bn + wc*32 + nb*16 + fr;
      float v = acc[nb][r];
      if (HAS_BIAS) v += bias[col];
      if (DO_ROWSCALE) v *= rs;
      if (OUT_BF16) ((u16*)Cv)[(size_t)row*N + col] = f2bf(v);
      else ((float*)Cv)[(size_t)row*N + col] = v;
    }
  }
}

// ---------------- GCN aggregation: 2 waves/node (edge-split), uint4 gathers ----------------
template<int OUT_BF16, int DO_RELU>
__global__ __launch_bounds__(256) void k_agg(const float* __restrict__ bias,
                                             void* __restrict__ outv) {
  __shared__ __align__(16) float red[2][512];
  const int t = threadIdx.x, w = t >> 6, lane = t & 63;
  const int pair = w >> 1, half = w & 1;
  const int i = blockIdx.x*2 + pair;
  const int d = lane * 8;
  const uint4* tbl = (const uint4*)g_hsh;
  float a[8] = {0,0,0,0,0,0,0,0};
  int e0 = g_off[i], e1 = g_off[i+1];
  int mid = (e0 + e1) >> 1;
  int es = half ? mid : e0;
  int ee = half ? e1 : mid;
  if (!half) acc8(tbl[i*64 + lane], a);   // self-loop counted once
  int e = es;
  for (; e + 4 <= ee; e += 4) {
    int s0 = g_adj[e+0], s1 = g_adj[e+1], s2 = g_adj[e+2], s3 = g_adj[e+3];
    uint4 v0 = tbl[s0*64 + lane];
    uint4 v1 = tbl[s1*64 + lane];
    uint4 v2 = tbl[s2*64 + lane];
    uint4 v3 = tbl[s3*64 + lane];
    acc8(v0, a); acc8(v1, a); acc8(v2, a); acc8(v3, a);
  }
  for (; e < ee; e++) acc8(tbl[g_adj[e]*64 + lane], a);
  if (!half) {
    #pragma unroll
    for (int q = 0; q < 8; q++) red[pair][d + q] = a[q];
  }
  __syncthreads();
  if (half) {
    #pragma unroll
    for (int q = 0; q < 8; q++) a[q] += red[pair][d + q];
    float di = g_dinv[i];
    const float4 b0 = *(const float4*)&bias[d];
    const float4 b1 = *(const float4*)&bias[d+4];
    a[0]=di*a[0]+b0.x; a[1]=di*a[1]+b0.y; a[2]=di*a[2]+b0.z; a[3]=di*a[3]+b0.w;
    a[4]=di*a[4]+b1.x; a[5]=di*a[5]+b1.y; a[6]=di*a[6]+b1.z; a[7]=di*a[7]+b1.w;
    if (DO_RELU) {
      #pragma unroll
      for (int q = 0; q < 8; q++) a[q] = fmaxf(a[q], 0.f);
    }
    if (OUT_BF16) {
      uint4 r;
      r.x = ((u32)f2bf(a[1])<<16) | f2bf(a[0]);
      r.y = ((u32)f2bf(a[3])<<16) | f2bf(a[2]);
      r.z = ((u32)f2bf(a[5])<<16) | f2bf(a[4]);
      r.w = ((u32)f2bf(a[7])<<16) | f2bf(a[6]);
      *(uint4*)&((u16*)outv)[i*512 + d] = r;
    } else {
      float4 r0; r0.x=a[0]; r0.y=a[1]; r0.z=a[2]; r0.w=a[3];
      float4 r1; r1.x=a[4]; r1.y=a[5]; r1.z=a[6]; r1.w=a[7];
      *(float4*)&((float*)outv)[i*512 + d]     = r0;
      *(float4*)&((float*)outv)[i*512 + d + 4] = r1;
    }
  }
}

// ---------------- host ----------------
static float* symf(const void* s) { void* p = nullptr; (void)hipGetSymbolAddress(&p, s); return (float*)p; }

extern "C" void kernel_launch(void* const* d_in, const int* in_sizes, int n_in,
                              void* d_out, int out_size, void* d_ws, size_t ws_size,
                              hipStream_t stream) {
  const float* feat = (const float*)d_in[0];
  const int*   edges= (const int*)  d_in[1];
  const float* linw = (const float*)d_in[2];
  const float* linb = (const float*)d_in[3];
  const float* ipw  = (const float*)d_in[4];
  const float* ipb  = (const float*)d_in[5];
  const float* outw = (const float*)d_in[6];
  const float* outb = (const float*)d_in[7];
  const float* ln1g = (const float*)d_in[8];
  const float* ln1b = (const float*)d_in[9];
  const float* fw1  = (const float*)d_in[10];
  const float* fb1  = (const float*)d_in[11];
  const float* fw2  = (const float*)d_in[12];
  const float* fb2  = (const float*)d_in[13];
  const float* ln2g = (const float*)d_in[14];
  const float* ln2b = (const float*)d_in[15];
  const float* W1g  = (const float*)d_in[16];
  const float* b1g  = (const float*)d_in[17];
  const float* W2g  = (const float*)d_in[18];
  const float* b2g  = (const float*)d_in[19];
  const float* W3g  = (const float*)d_in[20];
  const float* b3g  = (const float*)d_in[21];
  const float* W4g  = (const float*)d_in[22];
  const float* b4g  = (const float*)d_in[23];
  float* out = (float*)d_out;

  u16*   p_xmh = (u16*)symf(HIP_SYMBOL(g_xmh));
  u16*   p_hsh = (u16*)symf(HIP_SYMBOL(g_hsh));
  u16*   p_xgh = (u16*)symf(HIP_SYMBOL(g_xgh));
  u16*   p_wbf = (u16*)symf(HIP_SYMBOL(g_wbf));
  float* p_dinv= symf(HIP_SYMBOL(g_dinv));

  // fused prep pipeline (cc folded into fuse3 -> k_fuse4 eliminated)
  k_fuse1<<<140,  256, 0, stream>>>(ipw, ipb, linw, linb);
  k_fuse2<<<257,  256, 0, stream>>>(outw, outb, linw, linb, ln1g, ln1b, edges);
  k_fuse3<<<1953, 256, 0, stream>>>(feat, fw1, fb1, fw2, W1g, W2g, W3g, W4g);

  // FFN2 (on-the-fly h1, BK=128) + LN2 + mean + relu -> xmh  || CSR fill
  k_ffnln<<<768, 256, 0, stream>>>(fb2, ln2g, ln2b, edges);

  // GCN layers (32x64 tiles, BK=128; agg: 2 waves/node edge-split)
  k_mm64<1,1,0><<<dim3(8, 64), 256, 0, stream>>>(
      p_xmh, p_wbf + OFF_G1, p_hsh, NN, 512, 256, p_dinv, nullptr);
  k_agg<1,1><<<NN/2, 256, 0, stream>>>(b1g, p_xgh);
  k_mm64<1,1,0><<<dim3(8, 64), 256, 0, stream>>>(
      p_xgh, p_wbf + OFF_G2, p_hsh, NN, 512, 512, p_dinv, nullptr);
  k_agg<1,1><<<NN/2, 256, 0, stream>>>(b2g, p_xgh);
  k_mm64<1,1,0><<<dim3(8, 64), 256, 0, stream>>>(
      p_xgh, p_wbf + OFF_G3, p_hsh, NN, 512, 512, p_dinv, nullptr);
  k_agg<1,1><<<NN/2, 256, 0, stream>>>(b3g, p_xgh);
  k_mm64<1,1,0><<<dim3(8, 64), 256, 0, stream>>>(
      p_xgh, p_wbf + OFF_G4, p_hsh, NN, 512, 512, p_dinv, nullptr);
  k_agg<0,0><<<NN/2, 256, 0, stream>>>(b4g, out);
}

// Round 35
// 158.372 us; speedup vs baseline: 1.0053x; 1.0053x over previous
//
#include <hip/hip_runtime.h>
#include <hip/hip_bf16.h>
#include <math.h>

// Problem constants
#define NN   2048
#define FB   4
#define DD   256
#define EE   65536
#define NT   (NN*FB)
#define FFD  2048

typedef unsigned int u32;
typedef unsigned short u16;
typedef __attribute__((ext_vector_type(4))) float f32x4;
typedef __attribute__((ext_vector_type(8))) short bf16x8;

// weight buffer offsets (bf16 elements)
#define OFF_W2   0
#define OFF_G1   524288
#define OFF_G2   655360
#define OFF_G3   917504
#define OFF_G4   1179648
#define WBF_TOT  1441792

// ---------------- static device scratch ----------------
__device__ float g_A[768], g_B[768];
__device__ float g_coefA[4], g_coefC[4];
__device__ float g_meanv[6], g_G[36];
__device__ float g_Vx[8*DD];
__device__ u16   g_w1vh[FFD*8];             // W1V' bf16 (b1 folded into col 7)
__device__ float g_cc[NT*8];                // per-token LN1 coefficients
__device__ u16   g_xmh[NN*DD];
__device__ u16   g_hsh[NN*512];
__device__ u16   g_xgh[NN*512];
__device__ u16   g_wbf[WBF_TOT];
__device__ __align__(64) int g_degp[NN*16]; // line-padded atomic counters
__device__ __align__(64) int g_curp[NN*16];
__device__ int   g_off[NN+1], g_adj[EE];
__device__ float g_dinv[NN];

// ---------------- helpers ----------------
__device__ __forceinline__ u16 f2bf(float x) {
  u32 u = __float_as_uint(x);
  return (u16)((u + 0x7FFFu + ((u >> 16) & 1u)) >> 16);
}
__device__ __forceinline__ float bfl(u32 v) { return __uint_as_float(v << 16); }
__device__ __forceinline__ float bfh(u32 v) { return __uint_as_float(v & 0xffff0000u); }
__device__ __forceinline__ void gl_lds16(const void* g, void* l) {
  __builtin_amdgcn_global_load_lds(
      (const __attribute__((address_space(1))) u32*)g,
      (__attribute__((address_space(3))) u32*)l, 16, 0, 0);
}
__device__ __forceinline__ float qred(float v) {
  v += __shfl_xor(v, 1, 64);
  v += __shfl_xor(v, 2, 64);
  return v;
}
__device__ __forceinline__ void acc8(const uint4 v, float* a) {
  a[0]+=bfl(v.x); a[1]+=bfh(v.x);
  a[2]+=bfl(v.y); a[3]+=bfh(v.y);
  a[4]+=bfl(v.z); a[5]+=bfh(v.z);
  a[6]+=bfl(v.w); a[7]+=bfh(v.w);
}

// ========= FUSE-1: prep_ab (blk 0..11) || zero counters (blk 12..139) =========
__global__ __launch_bounds__(256) void k_fuse1(const float* __restrict__ ipw,
    const float* __restrict__ ipb, const float* __restrict__ linw,
    const float* __restrict__ linb) {
  __shared__ __align__(16) float sm[512];
  const int b = blockIdx.x, t = threadIdx.x;
  if (b < 12) {
    float* lw = sm; float* lb = sm + 256;
    lw[t] = linw[t]; lb[t] = linb[t];
    __syncthreads();
    int j = b*64 + (t>>2), c = t&3;
    const float4* row = (const float4*)&ipw[j*256 + c*64];
    float a = 0.f, bb = 0.f;
    #pragma unroll
    for (int q = 0; q < 16; q++) {
      float4 v = row[q]; int d0 = c*64 + q*4;
      a  += v.x*lw[d0] + v.y*lw[d0+1] + v.z*lw[d0+2] + v.w*lw[d0+3];
      bb += v.x*lb[d0] + v.y*lb[d0+1] + v.z*lb[d0+2] + v.w*lb[d0+3];
    }
    a = qred(a); bb = qred(bb);
    if (c == 0) { g_A[j] = a; g_B[j] = bb + ipb[j]; }
  } else {
    int i = (b - 12)*256 + t;
    if (i < NN*16) { g_degp[i] = 0; g_curp[i] = 0; }
  }
}

// ================= FUSE-2: prep_head (blk 0)  ||  deg (blk 1..256) =================
__global__ __launch_bounds__(256) void k_fuse2(const float* __restrict__ outw,
    const float* __restrict__ outb, const float* __restrict__ linw,
    const float* __restrict__ linb, const float* __restrict__ g1,
    const float* __restrict__ b1ln, const int* __restrict__ edges) {
  __shared__ __align__(16) float sm[512 + 4*27];
  const int b = blockIdx.x, t = threadIdx.x;
  if (b == 0) {
    int lane = t & 63, w = t >> 6;
    {
      float aq = g_A[w*64 + lane], ak = g_A[256 + w*64 + lane], bq = g_B[w*64 + lane];
      float pa = aq * ak, pc = bq * ak;
      #pragma unroll
      for (int o = 32; o > 0; o >>= 1) { pa += __shfl_down(pa, o, 64); pc += __shfl_down(pc, o, 64); }
      if (lane == 0) { g_coefA[w] = pa * 0.125f; g_coefC[w] = pc * 0.125f; }
    }
    float* A2 = sm; float* B2 = sm + 256; float* wred = sm + 512;
    A2[t] = g_A[512 + t]; B2[t] = g_B[512 + t];
    __syncthreads();
    const int d = t;
    const float4* row = (const float4*)&outw[d*256];
    float pv[4] = {0,0,0,0}, q0 = 0.f;
    #pragma unroll 8
    for (int q = 0; q < 64; q++) {
      float4 v = row[q]; int e0 = q*4; int h = q >> 4;
      pv[h] += v.x*A2[e0] + v.y*A2[e0+1] + v.z*A2[e0+2] + v.w*A2[e0+3];
      q0    += v.x*B2[e0] + v.y*B2[e0+1] + v.z*B2[e0+2] + v.w*B2[e0+3];
    }
    q0 += outb[d];
    float c0 = linb[d] + q0;
    float Mv[6] = { linw[d], pv[0], pv[1], pv[2], pv[3], c0 };
    float vals[27];
    { int idx = 0;
      #pragma unroll
      for (int k = 0; k < 6; k++) vals[idx++] = Mv[k];
      #pragma unroll
      for (int k = 0; k < 6; k++)
        #pragma unroll
        for (int l = 0; l < 6; l++) if (l >= k) vals[idx++] = Mv[k]*Mv[l];
    }
    #pragma unroll
    for (int k2 = 0; k2 < 27; k2++) {
      float v = vals[k2];
      #pragma unroll
      for (int o = 32; o > 0; o >>= 1) v += __shfl_down(v, o, 64);
      if (lane == 0) wred[w*27 + k2] = v;
    }
    __syncthreads();
    if (t < 27) {
      float s = wred[t] + wred[27 + t] + wred[54 + t] + wred[81 + t];
      if (t < 6) g_meanv[t] = s * (1.f/256.f);
      else {
        int p = t - 6, k = 0;
        while (p >= 6 - k) { p -= 6 - k; k++; }
        int l = k + p;
        g_G[k*6+l] = s; g_G[l*6+k] = s;
      }
    }
    #pragma unroll
    for (int k = 0; k < 6; k++) g_Vx[k*256 + d] = Mv[k] * g1[d];
    g_Vx[6*256 + d] = g1[d];
    g_Vx[7*256 + d] = b1ln[d];
  } else {
    int e = (b - 1)*256 + t;
    atomicAdd(&g_degp[edges[EE + e] * 16], 1);
  }
}

// ===== FUSE-3: attn_m + cc (0..511) || w1v->bf16+b1fold (512..543) || scan (544) || cvt (545..1952) =====
// cc computation folded from old k_fuse4: each attn block owns exactly tokens b*16..b*16+15
// (tok = tuple>>2), holds feat in LDS, and computes all 4 heads' m -> compute cc in-block.
__global__ __launch_bounds__(256) void k_fuse3(const float* __restrict__ feat,
    const float* __restrict__ w1, const float* __restrict__ fb1,
    const float* __restrict__ w2c, const float* __restrict__ W1c,
    const float* __restrict__ W2c, const float* __restrict__ W3c,
    const float* __restrict__ W4c) {
  __shared__ __align__(16) char smraw[35072];
  const int b = blockIdx.x, t = threadIdx.x;
  if (b < 512) {
    float* fs   = (float*)smraw;      // 8192 floats
    float* ss   = fs + 8192;          // 256
    float* ww   = ss + 256;           // 256
    float* marr = ww + 256;           // 64: m for this block's 64 tuples
    for (int i = t; i < 2048; i += 256) {
      const float4 v = *(const float4*)&feat[i*4];
      fs[0*2048+i] = v.x; fs[1*2048+i] = v.y; fs[2*2048+i] = v.z; fs[3*2048+i] = v.w;
    }
    __syncthreads();
    int tuple = b * 64 + (t >> 2);
    int c = t & 3;
    int h = tuple & 3, f = (tuple >> 2) & 3, n = tuple >> 4;
    float fi = fs[f*2048 + n];
    float tt = g_coefA[h] * fi + g_coefC[h];
    float s = 0.f, wsum = 0.f;
    int j0 = c * 512;
    for (int j = j0; j < j0 + 512; j++) {
      float fj = fs[f*2048 + j];
      float e = __expf(tt * fj);
      s += e; wsum += e * fj;
    }
    ss[(t>>2)*4 + c] = s; ww[(t>>2)*4 + c] = wsum;
    __syncthreads();
    if (c == 0) {
      float S = ss[(t>>2)*4] + ss[(t>>2)*4+1] + ss[(t>>2)*4+2] + ss[(t>>2)*4+3];
      float W = ww[(t>>2)*4] + ww[(t>>2)*4+1] + ww[(t>>2)*4+2] + ww[(t>>2)*4+3];
      marr[t>>2] = W / S;
    }
    __syncthreads();
    if (t < 16) {
      int tok = b*16 + t;
      int n2 = tok >> 2, f2 = tok & 3;
      float fi2 = fs[f2*2048 + n2];
      float u[6] = { fi2, marr[t*4+0], marr[t*4+1], marr[t*4+2], marr[t*4+3], 1.f };
      float mu = 0.f;
      #pragma unroll
      for (int k = 0; k < 6; k++) mu += g_meanv[k] * u[k];
      float q = 0.f;
      for (int k = 0; k < 6; k++)
        for (int l = 0; l < 6; l++) q += u[k] * g_G[k*6+l] * u[l];
      q *= (1.f/256.f);
      float var = q - mu * mu;
      float sc = rsqrtf(var + 1e-5f);
      float4 w0; w0.x = fi2*sc; w0.y = u[1]*sc; w0.z = u[2]*sc; w0.w = u[3]*sc;
      float4 w1v; w1v.x = u[4]*sc; w1v.y = sc; w1v.z = -mu*sc; w1v.w = 1.f;
      *(float4*)&g_cc[tok*8]     = w0;
      *(float4*)&g_cc[tok*8 + 4] = w1v;
    }
  } else if (b < 544) {
    // W1V'[j][k] = W1[j,:]·Vx_k  (+ b1[j] folded into k=7); bf16 out
    float* vx = (float*)smraw;
    #pragma unroll
    for (int k = 0; k < 8; k++) vx[k*256 + t] = g_Vx[k*256 + t];
    __syncthreads();
    int j = (b - 512)*64 + (t>>2), c = t&3;
    const float4* row = (const float4*)&w1[j*256 + c*64];
    float acc[8] = {0,0,0,0,0,0,0,0};
    #pragma unroll
    for (int q = 0; q < 16; q++) {
      float4 v = row[q]; int d0 = c*64 + q*4;
      #pragma unroll
      for (int k = 0; k < 8; k++)
        acc[k] += v.x*vx[k*256+d0] + v.y*vx[k*256+d0+1]
                + v.z*vx[k*256+d0+2] + v.w*vx[k*256+d0+3];
    }
    #pragma unroll
    for (int k = 0; k < 8; k++) acc[k] = qred(acc[k]);
    if (c == 0) {
      acc[7] += fb1[j];
      uint4 r;
      r.x = ((u32)f2bf(acc[1])<<16) | f2bf(acc[0]);
      r.y = ((u32)f2bf(acc[3])<<16) | f2bf(acc[2]);
      r.z = ((u32)f2bf(acc[5])<<16) | f2bf(acc[4]);
      r.w = ((u32)f2bf(acc[7])<<16) | f2bf(acc[6]);
      *(uint4*)&g_w1vh[j*8] = r;
    }
  } else if (b == 544) {
    int* wt = (int*)smraw;
    int base = t * 8;
    int v[8], ex[8], sum = 0;
    #pragma unroll
    for (int i = 0; i < 8; i++) { ex[i] = sum; v[i] = g_degp[(base+i)*16]; sum += v[i]; }
    int lane = t & 63, w = t >> 6;
    int inc = sum;
    #pragma unroll
    for (int o = 1; o < 64; o <<= 1) { int x = __shfl_up(inc, o, 64); if (lane >= o) inc += x; }
    if (lane == 63) wt[w] = inc;
    __syncthreads();
    int wb = 0;
    for (int j = 0; j < w; j++) wb += wt[j];
    int excl = wb + inc - sum;
    #pragma unroll
    for (int i = 0; i < 8; i++) {
      g_off[base+i] = excl + ex[i];
      g_dinv[base+i] = rsqrtf((float)(v[i] + 1));
    }
    if (t == 255) g_off[NN] = wb + inc;
  } else {
    int i = ((b - 545)*256 + t) * 4;
    const float* src; int off;
    if (i < OFF_G1)      { src = w2c; off = OFF_W2; }
    else if (i < OFF_G2) { src = W1c; off = OFF_G1; }
    else if (i < OFF_G3) { src = W2c; off = OFF_G2; }
    else if (i < OFF_G4) { src = W3c; off = OFF_G3; }
    else                 { src = W4c; off = OFF_G4; }
    float4 v = *(const float4*)&src[i - off];
    ushort4 r;
    r.x = f2bf(v.x); r.y = f2bf(v.y); r.z = f2bf(v.z); r.w = f2bf(v.w);
    *(ushort4*)&g_wbf[i] = r;
  }
}

// ====== FFN2 (on-the-fly h1) + LN2 + mean + relu -> g_xmh  ||  CSR fill (blk 512..767) ======
__global__ __launch_bounds__(256) void k_ffnln(const float* __restrict__ fb2,
    const float* __restrict__ ln2g, const float* __restrict__ ln2b,
    const int* __restrict__ edges) {
  __shared__ __align__(16) char smp[74752];
  u16*   Bsl  = (u16*)smp;                 // 64 KB: W2 tile [256 cols][128 k], swizzled 16B slots
  u16*   Asl  = (u16*)(smp + 65536);       // 4 KB:  h1 tile [16 rows][128 k]
  u16*   w1sl = (u16*)(smp + 69632);       // 4 KB:  2 x [128 rows][8] W1V' slices
  float* ccs  = (float*)(smp + 73728);     // 512 B: cc [16][8]
  float* part = (float*)(smp + 74240);     // 512 B: [4 waves][16 rows][2]

  const int b = blockIdx.x, t = threadIdx.x;
  if (b >= 512) {
    int e = (b - 512)*256 + t;
    int s = edges[e], d = edges[EE + e];
    int pos = atomicAdd(&g_curp[d*16], 1);
    g_adj[g_off[d] + pos] = s;
    return;
  }
  const int w = t >> 6, lane = t & 63, fr = lane & 15, gk = lane >> 4;
  const int tok0 = b * 16;
  const u16* W2p = g_wbf + OFF_W2;

  if (t < 32) ((float4*)ccs)[t] = ((const float4*)&g_cc[tok0*8])[t];
  if (w == 1) {
    #pragma unroll
    for (int hh = 0; hh < 2; hh++) {
      int p = hh*64 + lane;
      int q = (p & ~7) | ((p ^ (p >> 3)) & 7);   // involution
      gl_lds16(g_w1vh + (size_t)q*8, w1sl + (hh << 9));
    }
  }
  __syncthreads();

  const int arow = t >> 4, aslot = t & 15;
  float ac[8];
  #pragma unroll
  for (int k = 0; k < 8; k++) ac[k] = ccs[arow*8 + k];

  f32x4 acc[4] = {};
  for (int it = 0; it < 16; it++) {
    const int k0 = it << 7;
    const int cur = it & 1;
    #pragma unroll
    for (int c = 0; c < 16; c++) {
      int col0 = (w << 6) + (c << 2);
      int colL = col0 + (lane >> 4);
      int p = lane & 15;
      int q = (p & 8) | ((p ^ (colL & 7)) & 7);
      gl_lds16(W2p + (size_t)colL*FFD + k0 + q*8, Bsl + (col0 << 7));
    }
    if (w == 1 && it < 15) {
      #pragma unroll
      for (int hh = 0; hh < 2; hh++) {
        int p = hh*64 + lane;
        int q = (p & ~7) | ((p ^ (p >> 3)) & 7);
        gl_lds16(g_w1vh + (size_t)(k0 + 128 + q)*8, w1sl + ((cur ^ 1) << 10) + (hh << 9));
      }
    }
    {
      float h[8];
      #pragma unroll
      for (int e2 = 0; e2 < 8; e2++) {
        int ph = aslot*8 + (e2 ^ (aslot & 7));
        uint4 wv = *(const uint4*)&w1sl[(cur << 10) + ph*8];
        float s = ac[0]*bfl(wv.x) + ac[1]*bfh(wv.x)
                + ac[2]*bfl(wv.y) + ac[3]*bfh(wv.y)
                + ac[4]*bfl(wv.z) + ac[5]*bfh(wv.z)
                + ac[6]*bfl(wv.w) + ac[7]*bfh(wv.w);
        h[e2] = fmaxf(s, 0.f);
      }
      uint4 r;
      r.x = ((u32)f2bf(h[1])<<16) | f2bf(h[0]);
      r.y = ((u32)f2bf(h[3])<<16) | f2bf(h[2]);
      r.z = ((u32)f2bf(h[5])<<16) | f2bf(h[4]);
      r.w = ((u32)f2bf(h[7])<<16) | f2bf(h[6]);
      int ph = (aslot & 8) | ((aslot ^ (arow & 7)) & 7);
      *(uint4*)&Asl[(arow << 7) + (ph << 3)] = r;
    }
    __syncthreads();
    #pragma unroll
    for (int kk = 0; kk < 4; kk++) {
      int qa = (kk << 2) + gk;
      int pa = (qa & 8) | ((qa ^ (fr & 7)) & 7);
      bf16x8 af = *(const bf16x8*)&Asl[(fr << 7) + (pa << 3)];
      #pragma unroll
      for (int nb = 0; nb < 4; nb++) {
        int col = (w << 6) + (nb << 4) + fr;
        int pb = (qa & 8) | ((qa ^ (col & 7)) & 7);
        bf16x8 bv = *(const bf16x8*)&Bsl[(col << 7) + (pb << 3)];
        acc[nb] = __builtin_amdgcn_mfma_f32_16x16x32_bf16(af, bv, acc[nb], 0, 0, 0);
      }
    }
    __syncthreads();
  }

  #pragma unroll
  for (int nb = 0; nb < 4; nb++) {
    int col = (w << 6) + (nb << 4) + fr;
    float fb = fb2[col];
    #pragma unroll
    for (int r = 0; r < 4; r++) {
      int row = gk*4 + r;
      float x1 = 0.f;
      #pragma unroll
      for (int k = 0; k < 8; k++) x1 += ccs[row*8 + k] * g_Vx[k*256 + col];
      acc[nb][r] += fb + x1;
    }
  }
  float s1[4] = {0,0,0,0}, s2v[4] = {0,0,0,0};
  #pragma unroll
  for (int r = 0; r < 4; r++)
    #pragma unroll
    for (int nb = 0; nb < 4; nb++) {
      float v = acc[nb][r];
      s1[r] += v; s2v[r] += v*v;
    }
  #pragma unroll
  for (int o = 1; o < 16; o <<= 1) {
    #pragma unroll
    for (int r = 0; r < 4; r++) {
      s1[r]  += __shfl_xor(s1[r],  o, 64);
      s2v[r] += __shfl_xor(s2v[r], o, 64);
    }
  }
  if (fr == 0) {
    #pragma unroll
    for (int r = 0; r < 4; r++) {
      int row = gk*4 + r;
      part[(w*16 + row)*2 + 0] = s1[r];
      part[(w*16 + row)*2 + 1] = s2v[r];
    }
  }
  __syncthreads();
  float mu[4], inv[4];
  #pragma unroll
  for (int r = 0; r < 4; r++) {
    int row = gk*4 + r;
    float S1 = 0.f, S2 = 0.f;
    #pragma unroll
    for (int wv = 0; wv < 4; wv++) {
      S1 += part[(wv*16 + row)*2 + 0];
      S2 += part[(wv*16 + row)*2 + 1];
    }
    float m = S1 * (1.f/256.f);
    mu[r] = m;
    inv[r] = rsqrtf(S2 * (1.f/256.f) - m*m + 1e-5f);
  }
  const int node = b*4 + gk;
  #pragma unroll
  for (int nb = 0; nb < 4; nb++) {
    int col = (w << 6) + (nb << 4) + fr;
    float g = ln2g[col], bb = ln2b[col];
    float m = 0.f;
    #pragma unroll
    for (int r = 0; r < 4; r++)
      m += (acc[nb][r] - mu[r]) * inv[r] * g + bb;
    g_xmh[node*256 + col] = f2bf(fmaxf(m * 0.25f, 0.f));
  }
}

// ---------------- bf16 MFMA GEMM: C[M,N] = A[M,K] @ B[N,K]^T ----------------
// 32x64 tile, BK=128, 4 waves (2x2): wave = 16 rows x 32 cols. Grid (N/64, M/32).
template<int DO_ROWSCALE, int OUT_BF16, int HAS_BIAS>
__global__ __launch_bounds__(256) void k_mm64(
    const u16* __restrict__ A, const u16* __restrict__ Bm, void* __restrict__ Cv,
    int M, int N, int K,
    const float* __restrict__ rowscale, const float* __restrict__ bias)
{
  __shared__ u16 Asl[32*128];   // 8 KB
  __shared__ u16 Bsl[64*128];   // 16 KB
  const int t = threadIdx.x;
  const int w = t >> 6, lane = t & 63;
  const int bm = blockIdx.y * 32, bn = blockIdx.x * 64;
  const int wr = w >> 1, wc = w & 1;
  const int fr = lane & 15;
  const int gk = lane >> 4;
  f32x4 acc[2] = {};
  for (int k0 = 0; k0 < K; k0 += 128) {
    #pragma unroll
    for (int c = 0; c < 2; c++) {
      int row0 = (w << 3) + (c << 2);
      int rowL = row0 + (lane >> 4);
      int p = lane & 15;
      int q = (p & 8) | ((p ^ (rowL & 7)) & 7);
      gl_lds16(A + (size_t)(bm + rowL)*K + k0 + q*8, Asl + (row0 << 7));
    }
    #pragma unroll
    for (int c = 0; c < 4; c++) {
      int row0 = (w << 4) + (c << 2);
      int rowL = row0 + (lane >> 4);
      int p = lane & 15;
      int q = (p & 8) | ((p ^ (rowL & 7)) & 7);
      gl_lds16(Bm + (size_t)(bn + rowL)*K + k0 + q*8, Bsl + (row0 << 7));
    }
    __syncthreads();
    #pragma unroll
    for (int kk = 0; kk < 4; kk++) {
      int qa = (kk << 2) + gk;
      int row = wr*16 + fr;
      int pa = (qa & 8) | ((qa ^ (row & 7)) & 7);
      bf16x8 af = *(const bf16x8*)&Asl[(row << 7) + (pa << 3)];
      #pragma unroll
      for (int nb = 0; nb < 2; nb++) {
        int col = wc*32 + nb*16 + fr;
        int pb = (qa & 8) | ((qa ^ (col & 7)) & 7);
        bf16x8 bv = *(const bf16x8*)&Bsl[(col << 7) + (pb << 3)];
        acc[nb] = __builtin_amdgcn_mfma_f32_16x16x32_bf16(af, bv, acc[nb], 0, 0, 0);
      }
    }
    __syncthreads();
  }
  #pragma unroll
  for (int r = 0; r < 4; r++) {
    int row = bm + wr*16 + gk*4 + r;
    float rs = DO_ROWSCALE ? rowscale[row] : 1.f;
    #pragma unroll
    for (int nb = 0; nb < 2; nb++) {
      int col = bn + wc*32 + nb*16 + fr;
      float v = acc[nb][r];
      if (HAS_BIAS) v += bias[col];
      if (DO_ROWSCALE) v *= rs;
      if (OUT_BF16) ((u16*)Cv)[(size_t)row*N + col] = f2bf(v);
      else ((float*)Cv)[(size_t)row*N + col] = v;
    }
  }
}

// ---------------- GCN aggregation: 2 waves/node (edge-split), uint4 gathers ----------------
template<int OUT_BF16, int DO_RELU>
__global__ __launch_bounds__(256) void k_agg(const float* __restrict__ bias,
                                             void* __restrict__ outv) {
  __shared__ __align__(16) float red[2][512];
  const int t = threadIdx.x, w = t >> 6, lane = t & 63;
  const int pair = w >> 1, half = w & 1;
  const int i = blockIdx.x*2 + pair;
  const int d = lane * 8;
  const uint4* tbl = (const uint4*)g_hsh;
  float a[8] = {0,0,0,0,0,0,0,0};
  int e0 = g_off[i], e1 = g_off[i+1];
  int mid = (e0 + e1) >> 1;
  int es = half ? mid : e0;
  int ee = half ? e1 : mid;
  if (!half) acc8(tbl[i*64 + lane], a);   // self-loop counted once
  int e = es;
  for (; e + 4 <= ee; e += 4) {
    int s0 = g_adj[e+0], s1 = g_adj[e+1], s2 = g_adj[e+2], s3 = g_adj[e+3];
    uint4 v0 = tbl[s0*64 + lane];
    uint4 v1 = tbl[s1*64 + lane];
    uint4 v2 = tbl[s2*64 + lane];
    uint4 v3 = tbl[s3*64 + lane];
    acc8(v0, a); acc8(v1, a); acc8(v2, a); acc8(v3, a);
  }
  for (; e < ee; e++) acc8(tbl[g_adj[e]*64 + lane], a);
  if (!half) {
    #pragma unroll
    for (int q = 0; q < 8; q++) red[pair][d + q] = a[q];
  }
  __syncthreads();
  if (half) {
    #pragma unroll
    for (int q = 0; q < 8; q++) a[q] += red[pair][d + q];
    float di = g_dinv[i];
    const float4 b0 = *(const float4*)&bias[d];
    const float4 b1 = *(const float4*)&bias[d+4];
    a[0]=di*a[0]+b0.x; a[1]=di*a[1]+b0.y; a[2]=di*a[2]+b0.z; a[3]=di*a[3]+b0.w;
    a[4]=di*a[4]+b1.x; a[5]=di*a[5]+b1.y; a[6]=di*a[6]+b1.z; a[7]=di*a[7]+b1.w;
    if (DO_RELU) {
      #pragma unroll
      for (int q = 0; q < 8; q++) a[q] = fmaxf(a[q], 0.f);
    }
    if (OUT_BF16) {
      uint4 r;
      r.x = ((u32)f2bf(a[1])<<16) | f2bf(a[0]);
      r.y = ((u32)f2bf(a[3])<<16) | f2bf(a[2]);
      r.z = ((u32)f2bf(a[5])<<16) | f2bf(a[4]);
      r.w = ((u32)f2bf(a[7])<<16) | f2bf(a[6]);
      *(uint4*)&((u16*)outv)[i*512 + d] = r;
    } else {
      float4 r0; r0.x=a[0]; r0.y=a[1]; r0.z=a[2]; r0.w=a[3];
      float4 r1; r1.x=a[4]; r1.y=a[5]; r1.z=a[6]; r1.w=a[7];
      *(float4*)&((float*)outv)[i*512 + d]     = r0;
      *(float4*)&((float*)outv)[i*512 + d + 4] = r1;
    }
  }
}

// ---------------- host ----------------
static float* symf(const void* s) { void* p = nullptr; (void)hipGetSymbolAddress(&p, s); return (float*)p; }

extern "C" void kernel_launch(void* const* d_in, const int* in_sizes, int n_in,
                              void* d_out, int out_size, void* d_ws, size_t ws_size,
                              hipStream_t stream) {
  const float* feat = (const float*)d_in[0];
  const int*   edges= (const int*)  d_in[1];
  const float* linw = (const float*)d_in[2];
  const float* linb = (const float*)d_in[3];
  const float* ipw  = (const float*)d_in[4];
  const float* ipb  = (const float*)d_in[5];
  const float* outw = (const float*)d_in[6];
  const float* outb = (const float*)d_in[7];
  const float* ln1g = (const float*)d_in[8];
  const float* ln1b = (const float*)d_in[9];
  const float* fw1  = (const float*)d_in[10];
  const float* fb1  = (const float*)d_in[11];
  const float* fw2  = (const float*)d_in[12];
  const float* fb2  = (const float*)d_in[13];
  const float* ln2g = (const float*)d_in[14];
  const float* ln2b = (const float*)d_in[15];
  const float* W1g  = (const float*)d_in[16];
  const float* b1g  = (const float*)d_in[17];
  const float* W2g  = (const float*)d_in[18];
  const float* b2g  = (const float*)d_in[19];
  const float* W3g  = (const float*)d_in[20];
  const float* b3g  = (const float*)d_in[21];
  const float* W4g  = (const float*)d_in[22];
  const float* b4g  = (const float*)d_in[23];
  float* out = (float*)d_out;

  u16*   p_xmh = (u16*)symf(HIP_SYMBOL(g_xmh));
  u16*   p_hsh = (u16*)symf(HIP_SYMBOL(g_hsh));
  u16*   p_xgh = (u16*)symf(HIP_SYMBOL(g_xgh));
  u16*   p_wbf = (u16*)symf(HIP_SYMBOL(g_wbf));
  float* p_dinv= symf(HIP_SYMBOL(g_dinv));

  // fused prep pipeline (cc folded into fuse3 -> k_fuse4 eliminated)
  k_fuse1<<<140,  256, 0, stream>>>(ipw, ipb, linw, linb);
  k_fuse2<<<257,  256, 0, stream>>>(outw, outb, linw, linb, ln1g, ln1b, edges);
  k_fuse3<<<1953, 256, 0, stream>>>(feat, fw1, fb1, fw2, W1g, W2g, W3g, W4g);

  // FFN2 (on-the-fly h1, BK=128) + LN2 + mean + relu -> xmh  || CSR fill
  k_ffnln<<<768, 256, 0, stream>>>(fb2, ln2g, ln2b, edges);

  // GCN layers (32x64 tiles, BK=128; agg: 2 waves/node edge-split)
  k_mm64<1,1,0><<<dim3(8, 64), 256, 0, stream>>>(
      p_xmh, p_wbf + OFF_G1, p_hsh, NN, 512, 256, p_dinv, nullptr);
  k_agg<1,1><<<NN/2, 256, 0, stream>>>(b1g, p_xgh);
  k_mm64<1,1,0><<<dim3(8, 64), 256, 0, stream>>>(
      p_xgh, p_wbf + OFF_G2, p_hsh, NN, 512, 512, p_dinv, nullptr);
  k_agg<1,1><<<NN/2, 256, 0, stream>>>(b2g, p_xgh);
  k_mm64<1,1,0><<<dim3(8, 64), 256, 0, stream>>>(
      p_xgh, p_wbf + OFF_G3, p_hsh, NN, 512, 512, p_dinv, nullptr);
  k_agg<1,1><<<NN/2, 256, 0, stream>>>(b3g, p_xgh);
  k_mm64<1,1,0><<<dim3(8, 64), 256, 0, stream>>>(
      p_xgh, p_wbf + OFF_G4, p_hsh, NN, 512, 512, p_dinv, nullptr);
  k_agg<0,0><<<NN/2, 256, 0, stream>>>(b4g, out);
}